// Round 3
// baseline (735.713 us; speedup 1.0000x reference)
//
#include <hip/hip_runtime.h>
#include <stdint.h>
#include <math.h>

typedef __attribute__((ext_vector_type(8))) short short8;
typedef __attribute__((ext_vector_type(4))) float floatx4;

#define B_DIM 2048
#define O_DIM 512
#define H_DIM 1024
#define P_DIM 1024
#define C_DIM 512
#define K_BIG 2560   // H + P + C
#define TAU 0.25f
#define OMT 0.75f

// s_waitcnt imm: vmcnt(n) only; exp=7, lgkm=15 (don't wait)
#define VMCNT(n) ((n) | 0x0F70)

__device__ inline short f2bf(float f) {
  uint32_t u = __float_as_uint(f);
  u += 0x7FFFu + ((u >> 16) & 1u);   // round-to-nearest-even
  return (short)(u >> 16);
}

__device__ inline float sigmoidf_(float x) {
  return 1.0f / (1.0f + __expf(-x));
}

__device__ inline void async_copy16(const void* g, void* l) {
  __builtin_amdgcn_global_load_lds((__attribute__((address_space(1))) void*)g,
                                   (__attribute__((address_space(3))) void*)l,
                                   16, 0, 0);
}

// ---------------------------------------------------------------------------
// GEMM core: 64(M) x 64(N) block tile, BK=32, 4 waves stacked in M (16 rows
// each, full 64 N). A staged via global_load_lds into double-buffered LDS
// (2 x 4KB), column-chunk swizzled for conflict-free ds_read_b128.
// B is NOT staged: weights pre-swizzled into MFMA B-frag order; each wave
// loads 4 B-frags (1KB coalesced each) global->VGPR, double-buffered in regs.
// Per wave per K-iter: 1 ds_read_b128 + 4 global dwordx4 + 4 MFMA.
// Bswz layout: frag (nb = n/16, kc = k/32): ((nb*kcn + kc)*64 + lane)*8 shorts,
// lane holds BT[nb*16 + (lane&15)][kc*32 + (lane>>4)*8 + e].
// ---------------------------------------------------------------------------
__device__ inline void gemm_core2(const short* __restrict__ A, int lda,
                                  const short* __restrict__ Bswz, int kcn,
                                  int nb0, int K, short* lds, floatx4 acc[4]) {
  const int tid = threadIdx.x;
  const int row = tid >> 2;                 // A tile row 0..63
  const int ccs = tid & 3;                  // LDS chunk slot
  const int cc  = ccs ^ ((row >> 1) & 3);   // swizzled global column chunk
  const short* gA = A + row * lda + cc * 8;

  const int lane = tid & 63;
  const int fm = lane & 15, hi = lane >> 4;
  const int w = tid >> 6;                   // wave id = M sub-tile
  const int aoff = (w * 16 + fm) * 32 + (hi ^ ((fm >> 1) & 3)) * 8;

  const short8* Bf[4];
#pragma unroll
  for (int j = 0; j < 4; ++j)
    Bf[j] = (const short8*)Bswz + (size_t)(nb0 + j) * kcn * 64 + lane;

  short8 bcur[4], bnxt[4];

  // prefetch tile 0
  async_copy16(gA, lds + tid * 8);
#pragma unroll
  for (int j = 0; j < 4; ++j) bcur[j] = Bf[j][0];

  const int nIter = K / 32;
  for (int it = 0; it < nIter; ++it) {
    const int cur = (it & 1) * 2048;
    const int nxt = cur ^ 2048;
    __builtin_amdgcn_s_barrier();           // nxt buf free (all waves past reads)
    if (it + 1 < nIter) {
      asm volatile("" ::: "memory");
      async_copy16(gA + (it + 1) * 32, lds + nxt + tid * 8);
#pragma unroll
      for (int j = 0; j < 4; ++j) bnxt[j] = Bf[j][(it + 1) * 64];
      asm volatile("" ::: "memory");
      // outstanding after wait: A(it+1) stage + 4 B(it+1) loads = 5
      // => A(it) in LDS, B(it) in regs; prefetch stays in flight.
      __builtin_amdgcn_s_waitcnt(VMCNT(5));
    } else {
      __builtin_amdgcn_s_waitcnt(VMCNT(0));
    }
    __builtin_amdgcn_s_barrier();           // all waves' A(it) chunks in LDS

    short8 afr = *(const short8*)&lds[cur + aoff];
#pragma unroll
    for (int j = 0; j < 4; ++j)
      acc[j] = __builtin_amdgcn_mfma_f32_16x16x32_bf16(afr, bcur[j], acc[j], 0, 0, 0);
#pragma unroll
    for (int j = 0; j < 4; ++j) bcur[j] = bnxt[j];
  }
}

// ---------------- setup kernels ----------------

// Generic fp32 [K][N] (ld=N) -> bf16 B-frag-swizzled dst, via LDS transpose.
// Block handles 64k x 64n. zdiag: zero where global k == global n (w_pp).
__global__ __launch_bounds__(256) void k_swz(const float* __restrict__ W, int K, int N,
                                             short* __restrict__ dst, int Ktot32,
                                             int koff32, int zdiag) {
  __shared__ short lt[64 * 64];
  int nbb = N >> 6;
  int bn = blockIdx.x % nbb, bk = blockIdx.x / nbb;
  int n0 = bn * 64, k0 = bk * 64;
  int t = threadIdx.x;
  int kl = t >> 4, n4 = (t & 15) * 4;
#pragma unroll
  for (int r = 0; r < 4; ++r) {
    int k = kl + r * 16;
    const float* src = W + (size_t)(k0 + k) * N + n0 + n4;
#pragma unroll
    for (int e = 0; e < 4; ++e) {
      float v = src[e];
      if (zdiag && (k0 + k == n0 + n4 + e)) v = 0.f;
      lt[k * 64 + n4 + e] = f2bf(v);
    }
  }
  __syncthreads();
#pragma unroll
  for (int h = 0; h < 2; ++h) {
    int c = h * 256 + t;                    // chunk: (nbl*2 + kcl)*64 + lane
    int lane = c & 63, kcl = (c >> 6) & 1, nbl = c >> 7;
    int n = nbl * 16 + (lane & 15);
    int kk = kcl * 32 + (lane >> 4) * 8;
    short8 v;
#pragma unroll
    for (int e = 0; e < 8; ++e) v[e] = lt[(kk + e) * 64 + n];
    int gnb = (n0 >> 4) + nbl, gkc = koff32 + (k0 >> 5) + kcl;
    *(short8*)&dst[(((size_t)gnb * Ktot32 + gkc) * 64 + lane) * 8] = v;
  }
}

__global__ void k_build_in(const float* __restrict__ inp, short* __restrict__ inb) {
  int idx = blockIdx.x * 256 + threadIdx.x;       // 2048*512
  inb[idx] = f2bf(inp[idx]);
}

__global__ void k_init(uint32_t* __restrict__ X0, float* __restrict__ p, float* __restrict__ c) {
  int i = blockIdx.x * 256 + threadIdx.x;         // sized for X0 words
  X0[i] = 0x3F003F00u;                            // two bf16 0.5
  if (i < B_DIM * P_DIM) p[i] = 0.f;
  if (i < B_DIM * C_DIM) c[i] = 0.f;
}

// oh = inputs @ w_oh + bias_h   (M=2048,N=1024,K=512) grid 32x16=512
__global__ __launch_bounds__(256, 3) void k_gemm_oh(const short* __restrict__ inb,
                                                    const short* __restrict__ WohS,
                                                    const float* __restrict__ bias_h,
                                                    float* __restrict__ oh) {
  __shared__ short lds[4096];
  floatx4 acc[4] = {};
  int m0 = (blockIdx.x >> 4) * 64;
  int n0 = (blockIdx.x & 15) * 64;
  gemm_core2(inb + (size_t)m0 * O_DIM, O_DIM, WohS, O_DIM / 32, (n0 >> 4), O_DIM, lds, acc);
  const int lane = threadIdx.x & 63;
  const int fm = lane & 15, hi = lane >> 4;
  const int w = threadIdx.x >> 6;
#pragma unroll
  for (int j = 0; j < 4; ++j) {
    int n = n0 + j * 16 + fm;
    float bh = bias_h[n];
#pragma unroll
    for (int r = 0; r < 4; ++r) {
      int m = m0 + w * 16 + hi * 4 + r;
      oh[(size_t)m * H_DIM + n] = acc[j][r] + bh;
    }
  }
}

// ---------------- per-timestep fused kernel ----------------
// blocks [0,512): big GEMM X(2048x2560)@WbS -> p/ap; n_tile = bx&15 so the
//   CU-sharing pair (bx, bx+256) reads the same B frags (L1 reuse).
// blocks [512,768): small GEMM ap(2048x1024)@WpcS -> c/ac.
__global__ __launch_bounds__(256, 3) void k_step(const short* __restrict__ Xc,
                                                 short* __restrict__ Xn,
                                                 const short* __restrict__ WbS,
                                                 const short* __restrict__ WpcS,
                                                 const float* __restrict__ bias_p,
                                                 const float* __restrict__ bias_c,
                                                 const float* __restrict__ oh,
                                                 float* __restrict__ p,
                                                 float* __restrict__ c,
                                                 float* __restrict__ out_t,
                                                 float ct) {
  __shared__ short lds[4096];
  floatx4 acc[4] = {};
  const int lane = threadIdx.x & 63;
  const int fm = lane & 15, hi = lane >> 4;
  const int w = threadIdx.x >> 6;
  const int bx = blockIdx.x;

  if (bx < 512) {
    int m0 = (bx >> 4) * 64;
    int n0 = (bx & 15) * 64;
    gemm_core2(Xc + (size_t)m0 * K_BIG, K_BIG, WbS, K_BIG / 32, (n0 >> 4), K_BIG, lds, acc);
#pragma unroll
    for (int j = 0; j < 4; ++j) {
      int n = n0 + j * 16 + fm;
      float bp = bias_p[n];
#pragma unroll
      for (int r = 0; r < 4; ++r) {
        int m = m0 + w * 16 + hi * 4 + r;
        size_t o = (size_t)m * P_DIM + n;
        float pn = TAU * (acc[j][r] + bp) + OMT * p[o];
        p[o] = pn;
        float ap = sigmoidf_(pn);
        out_t[o] = ap;
        Xn[(size_t)m * K_BIG + H_DIM + n] = f2bf(ap);
        float ah = sigmoidf_(ct * oh[o]);
        Xn[(size_t)m * K_BIG + n] = f2bf(ah);
      }
    }
  } else {
    int v = bx - 512;
    int m0 = (v >> 3) * 64;
    int n0 = (v & 7) * 64;
    gemm_core2(Xc + (size_t)m0 * K_BIG + H_DIM, K_BIG, WpcS, P_DIM / 32, (n0 >> 4), P_DIM, lds, acc);
#pragma unroll
    for (int j = 0; j < 4; ++j) {
      int n = n0 + j * 16 + fm;
      float bc = bias_c[n];
#pragma unroll
      for (int r = 0; r < 4; ++r) {
        int m = m0 + w * 16 + hi * 4 + r;
        size_t o = (size_t)m * C_DIM + n;
        float cn = TAU * (acc[j][r] + bc) + OMT * c[o];
        c[o] = cn;
        Xn[(size_t)m * K_BIG + H_DIM + P_DIM + n] = f2bf(sigmoidf_(cn));
      }
    }
  }
}

extern "C" void kernel_launch(void* const* d_in, const int* in_sizes, int n_in,
                              void* d_out, int out_size, void* d_ws, size_t ws_size,
                              hipStream_t stream) {
  const float* inputs = (const float*)d_in[0];
  const float* w_oh   = (const float*)d_in[1];
  const float* w_hp   = (const float*)d_in[2];
  const float* w_pp   = (const float*)d_in[3];
  const float* w_pc   = (const float*)d_in[4];
  const float* w_cp   = (const float*)d_in[5];
  const float* bias_h = (const float*)d_in[6];
  const float* bias_p = (const float*)d_in[7];
  const float* bias_c = (const float*)d_in[8];
  float* out = (float*)d_out;

  char* ws = (char*)d_ws;
  auto alloc = [&](size_t bytes) {
    char* q = ws;
    ws += (bytes + 255) & ~(size_t)255;
    return q;
  };
  short* WbS  = (short*)alloc((size_t)P_DIM * K_BIG * 2);      // 5 MB  (B-frag swizzled)
  short* WpcS = (short*)alloc((size_t)C_DIM * P_DIM * 2);      // 1 MB
  short* WohS = (short*)alloc((size_t)H_DIM * O_DIM * 2);      // 1 MB
  short* inb  = (short*)alloc((size_t)B_DIM * O_DIM * 2);      // 2 MB
  float* oh   = (float*)alloc((size_t)B_DIM * H_DIM * 4);      // 8 MB
  short* X0   = (short*)alloc((size_t)B_DIM * K_BIG * 2);      // 10.5 MB
  short* X1   = (short*)alloc((size_t)B_DIM * K_BIG * 2);      // 10.5 MB
  float* p    = (float*)alloc((size_t)B_DIM * P_DIM * 4);      // 8 MB
  float* c    = (float*)alloc((size_t)B_DIM * C_DIM * 4);      // 4 MB

  // setup
  k_init<<<dim3((B_DIM * K_BIG / 2) / 256), 256, 0, stream>>>((uint32_t*)X0, p, c);
  // WbS = [w_hp ; w_pp(diag=0) ; w_cp] swizzled, Ktot=2560
  k_swz<<<dim3(16 * 16), 256, 0, stream>>>(w_hp, 1024, 1024, WbS, K_BIG / 32, 0, 0);
  k_swz<<<dim3(16 * 16), 256, 0, stream>>>(w_pp, 1024, 1024, WbS, K_BIG / 32, 32, 1);
  k_swz<<<dim3(16 * 8),  256, 0, stream>>>(w_cp, 512, 1024, WbS, K_BIG / 32, 64, 0);
  k_swz<<<dim3(8 * 16),  256, 0, stream>>>(w_pc, 1024, 512, WpcS, P_DIM / 32, 0, 0);
  k_swz<<<dim3(16 * 8),  256, 0, stream>>>(w_oh, 512, 1024, WohS, O_DIM / 32, 0, 0);
  k_build_in<<<dim3((B_DIM * O_DIM) / 256), 256, 0, stream>>>(inputs, inb);
  k_gemm_oh<<<dim3(512), 256, 0, stream>>>(inb, WohS, bias_h, oh);

  // 12 recurrent steps
  short* Xbuf[2] = {X0, X1};
  for (int t = 1; t <= 12; ++t) {
    float ct = 1.0f - powf(OMT, (float)t);
    k_step<<<dim3(768), 256, 0, stream>>>(Xbuf[(t + 1) & 1], Xbuf[t & 1],
                                          WbS, WpcS, bias_p, bias_c, oh, p, c,
                                          out + (size_t)(t - 1) * B_DIM * P_DIM, ct);
  }
}